// Round 9
// baseline (187.173 us; speedup 1.0000x reference)
//
#include <hip/hip_runtime.h>
#include <math.h>

#define NPTS 2048
#define BATCH 16
#define KNN 16
#define HID 128
#define NPOINTS (BATCH * NPTS)   // 32768
#define QPB 16         // queries per block (8 waves x 2 queries/wave)
#define CAP 64         // compacted-candidate capacity per query (m ~ 18.4 avg)
#define KNN_BLOCKS (NPOINTS / QPB)   // 2048

typedef __attribute__((ext_vector_type(8))) short bf16x8;
typedef __attribute__((ext_vector_type(4))) float f32x4;

__device__ inline unsigned short f2bf(float f) {    // RNE f32 -> bf16 bits
    unsigned u = __float_as_uint(f);
    return (unsigned short)((u + 0x7FFFu + ((u >> 16) & 1u)) >> 16);
}
__device__ inline float bflo(unsigned v) { return __uint_as_float(v << 16); }
__device__ inline float bfhi(unsigned v) { return __uint_as_float(v & 0xFFFF0000u); }

// x1/x2 ROW-MAJOR bf16 [32768][128]; weights chunked-T (wT[cc][h][8]).
//
// R18: harness floor identified (268MB fill @73% HBM peak ~46us + ~12 small
// memsets/iter -- not addressable). knn is the only lever (~42us, DS-pipe
// bound: 32 ds_read_b128/query dominates). Fix: 2 QUERIES PER WAVE -- one
// candidate read feeds two distance computations; shared bitonic selects;
// packed u64 (key<<32|idx) compaction (1 ds_write_b64); W1 loads amortized.
// Per-query DS ~700 -> ~450 cyc. Predicted knn ~31us, total ~148us.

// ---------------------------------------------------------------------------
// kNN + fused layer 1. One wave per TWO query rows.
// ---------------------------------------------------------------------------
__global__ __launch_bounds__(512) void knn_kernel(
    const float* __restrict__ pc, int* __restrict__ nbr,
    const float* __restrict__ W1r, const float* __restrict__ b1,
    const float* __restrict__ W1s, unsigned short* __restrict__ x1,
    const float* __restrict__ W2r, const float* __restrict__ W2s,
    const float* __restrict__ W3r, const float* __restrict__ W3s,
    unsigned short* __restrict__ wT)
{
    __shared__ __align__(16) float4 pts[NPTS];              // 32 KB
    __shared__ unsigned long long cand[QPB][CAP];           // 8 KB
    __shared__ __align__(16) unsigned short xst[QPB][HID];  // 4 KB

    if (blockIdx.x >= KNN_BLOCKS) {
        // ---- folded weight conversion: 32 blocks x 512 thr x 4 elems ------
        int g = (blockIdx.x - KNN_BLOCKS) * 2048 + (int)threadIdx.x * 4;
        #pragma unroll
        for (int u = 0; u < 4; ++u) {
            int g2 = g + u;
            int mm = g2 >> 14;
            int e = g2 & 16383;
            int r = e >> 7, cch = e & 127;
            const float* s = (mm == 0) ? W2r : (mm == 1) ? W2s
                           : (mm == 2) ? W3r : W3s;
            wT[mm * 16384 + ((cch >> 3) * 128 + r) * 8 + (cch & 7)] = f2bf(s[e]);
        }
        return;
    }

    const int b = blockIdx.x >> 7;                    // 128 blocks per batch
    const int rblk = blockIdx.x & 127;
    const float* p = pc + (size_t)b * NPTS * 3;

    for (int t = threadIdx.x; t < NPTS; t += 512) {
        float x = p[t * 3 + 0], y = p[t * 3 + 1], z = p[t * 3 + 2];
        pts[t] = make_float4(x, y, z, x * x + y * y + z * z);
    }
    __syncthreads();

    const int w = threadIdx.x >> 6;
    const int lane = threadIdx.x & 63;
    const int r0q = w * 2, r1q = w * 2 + 1;           // query rows in block
    const int i0 = rblk * QPB + r0q, i1 = i0 + 1;     // query rows in batch
    const float4 pi0 = pts[i0];
    const float4 pi1 = pts[i1];
    const float p0w16 = pi0.w + 16.0f;
    const float p1w16 = pi1.w + 16.0f;

    unsigned key0[32], key1[32];                      // STATIC indexing only!
    unsigned km0 = 0xFFFFFFFFu, km1 = 0xFFFFFFFFu;
    #pragma unroll
    for (int t = 0; t < 32; ++t) {
        float4 c = pts[t * 64 + lane];                // ONE read, TWO queries
        float dot0 = fmaf(pi0.x, c.x, fmaf(pi0.y, c.y, pi0.z * c.z));
        float dot1 = fmaf(pi1.x, c.x, fmaf(pi1.y, c.y, pi1.z * c.z));
        key0[t] = __float_as_uint(fmaf(-2.0f, dot0, p0w16 + c.w));
        key1[t] = __float_as_uint(fmaf(-2.0f, dot1, p1w16 + c.w));
        km0 = min(km0, key0[t]);
        km1 = min(km1, key1[t]);
    }

    // ---- T0 = 16th-smallest of 64 per-lane minima; both queries share sel -
    unsigned v0 = km0, v1 = km1;
    #pragma unroll
    for (int k = 2; k <= 64; k <<= 1) {
        #pragma unroll
        for (int j = k >> 1; j > 0; j >>= 1) {
            unsigned o0 = (unsigned)__shfl_xor((int)v0, j, 64);
            unsigned o1 = (unsigned)__shfl_xor((int)v1, j, 64);
            bool sel = ((lane & k) == 0) == ((lane & j) == 0);
            v0 = sel ? min(v0, o0) : max(v0, o0);
            v1 = sel ? min(v1, o1) : max(v1, o1);
        }
    }
    const unsigned T00 = (unsigned)__shfl((int)v0, 15, 64);
    const unsigned T01 = (unsigned)__shfl((int)v1, 15, 64);
    // >=16 candidates <= T0 and T0 >= true 16th => superset of the top-16.

    // ---- compaction (fully unrolled; packed u64 = key<<32|idx) ------------
    unsigned base0 = 0, base1 = 0;
    #pragma unroll
    for (int t = 0; t < 32; ++t) {
        bool pr0 = key0[t] <= T00;
        unsigned long long mk0 = __ballot(pr0);
        if (mk0) {
            unsigned pf = __builtin_amdgcn_mbcnt_hi(
                (unsigned)(mk0 >> 32),
                __builtin_amdgcn_mbcnt_lo((unsigned)mk0, 0));
            unsigned pos = base0 + pf;
            if (pr0 && pos < CAP)
                cand[r0q][pos] = ((unsigned long long)key0[t] << 32)
                               | (unsigned)(t * 64 + lane);
            base0 += (unsigned)__popcll(mk0);
        }
        bool pr1 = key1[t] <= T01;
        unsigned long long mk1 = __ballot(pr1);
        if (mk1) {
            unsigned pf = __builtin_amdgcn_mbcnt_hi(
                (unsigned)(mk1 >> 32),
                __builtin_amdgcn_mbcnt_lo((unsigned)mk1, 0));
            unsigned pos = base1 + pf;
            if (pr1 && pos < CAP)
                cand[r1q][pos] = ((unsigned long long)key1[t] << 32)
                               | (unsigned)(t * 64 + lane);
            base1 += (unsigned)__popcll(mk1);
        }
    }
    const int m0 = (int)base0, m1 = (int)base1;

    int* out0 = nbr + ((size_t)b * NPTS + i0) * KNN;
    int* out1 = nbr + ((size_t)b * NPTS + i1) * KNN;
    float ax0 = 0.f, ay0 = 0.f, az0 = 0.f;
    float ax1 = 0.f, ay1 = 0.f, az1 = 0.f;

    // ---- rank + emit, query 0 --------------------------------------------
    if (m0 <= CAP) {
        unsigned long long c0 = (lane < m0) ? cand[r0q][lane] : ~0ULL;
        int rk = 0;
        #pragma unroll 2
        for (int jj = 0; jj < m0; ++jj)
            rk += (cand[r0q][jj] < c0);               // u64 unique => strict
        if (lane < m0 && rk < KNN) {
            unsigned j = (unsigned)c0;
            out0[rk] = (int)j;
            float4 q = pts[j]; ax0 += q.x; ay0 += q.y; az0 += q.z;
        }
    } else {
        // exact fallback (never taken w/ random data): recompute from LDS
        auto keyat = [&](int t) -> unsigned {
            float4 c = pts[t * 64 + lane];
            float dot = fmaf(pi0.x, c.x, fmaf(pi0.y, c.y, pi0.z * c.z));
            return __float_as_uint(fmaf(-2.0f, dot, p0w16 + c.w));
        };
        unsigned T = 0;
        #pragma unroll 1
        for (int bit = 31; bit >= 0; --bit) {
            unsigned trial = T | (1u << bit);
            int cnt = 0;
            #pragma unroll 1
            for (int t = 0; t < 32; ++t) cnt += (keyat(t) < trial);
            #pragma unroll
            for (int off = 32; off; off >>= 1) cnt += __shfl_xor(cnt, off, 64);
            if (cnt < KNN) T = trial;
        }
        unsigned bs = 0;
        #pragma unroll 1
        for (int t = 0; t < 32; ++t) {
            bool p1 = keyat(t) < T;
            unsigned long long mask = __ballot(p1);
            if (mask) {
                unsigned pf = __builtin_amdgcn_mbcnt_hi(
                    (unsigned)(mask >> 32),
                    __builtin_amdgcn_mbcnt_lo((unsigned)mask, 0));
                if (p1) {
                    out0[bs + pf] = t * 64 + lane;
                    float4 q = pts[t * 64 + lane];
                    ax0 += q.x; ay0 += q.y; az0 += q.z;
                }
                bs += (unsigned)__popcll(mask);
            }
        }
        #pragma unroll 1
        for (int t = 0; t < 32 && bs < KNN; ++t) {
            bool p2 = keyat(t) == T;
            unsigned long long mask = __ballot(p2);
            if (mask) {
                unsigned pf = __builtin_amdgcn_mbcnt_hi(
                    (unsigned)(mask >> 32),
                    __builtin_amdgcn_mbcnt_lo((unsigned)mask, 0));
                unsigned pos = bs + pf;
                if (p2 && pos < KNN) {
                    out0[pos] = t * 64 + lane;
                    float4 q = pts[t * 64 + lane];
                    ax0 += q.x; ay0 += q.y; az0 += q.z;
                }
                bs += (unsigned)__popcll(mask);
            }
        }
    }

    // ---- rank + emit, query 1 --------------------------------------------
    if (m1 <= CAP) {
        unsigned long long c1 = (lane < m1) ? cand[r1q][lane] : ~0ULL;
        int rk = 0;
        #pragma unroll 2
        for (int jj = 0; jj < m1; ++jj)
            rk += (cand[r1q][jj] < c1);
        if (lane < m1 && rk < KNN) {
            unsigned j = (unsigned)c1;
            out1[rk] = (int)j;
            float4 q = pts[j]; ax1 += q.x; ay1 += q.y; az1 += q.z;
        }
    } else {
        auto keyat = [&](int t) -> unsigned {
            float4 c = pts[t * 64 + lane];
            float dot = fmaf(pi1.x, c.x, fmaf(pi1.y, c.y, pi1.z * c.z));
            return __float_as_uint(fmaf(-2.0f, dot, p1w16 + c.w));
        };
        unsigned T = 0;
        #pragma unroll 1
        for (int bit = 31; bit >= 0; --bit) {
            unsigned trial = T | (1u << bit);
            int cnt = 0;
            #pragma unroll 1
            for (int t = 0; t < 32; ++t) cnt += (keyat(t) < trial);
            #pragma unroll
            for (int off = 32; off; off >>= 1) cnt += __shfl_xor(cnt, off, 64);
            if (cnt < KNN) T = trial;
        }
        unsigned bs = 0;
        #pragma unroll 1
        for (int t = 0; t < 32; ++t) {
            bool p1 = keyat(t) < T;
            unsigned long long mask = __ballot(p1);
            if (mask) {
                unsigned pf = __builtin_amdgcn_mbcnt_hi(
                    (unsigned)(mask >> 32),
                    __builtin_amdgcn_mbcnt_lo((unsigned)mask, 0));
                if (p1) {
                    out1[bs + pf] = t * 64 + lane;
                    float4 q = pts[t * 64 + lane];
                    ax1 += q.x; ay1 += q.y; az1 += q.z;
                }
                bs += (unsigned)__popcll(mask);
            }
        }
        #pragma unroll 1
        for (int t = 0; t < 32 && bs < KNN; ++t) {
            bool p2 = keyat(t) == T;
            unsigned long long mask = __ballot(p2);
            if (mask) {
                unsigned pf = __builtin_amdgcn_mbcnt_hi(
                    (unsigned)(mask >> 32),
                    __builtin_amdgcn_mbcnt_lo((unsigned)mask, 0));
                unsigned pos = bs + pf;
                if (p2 && pos < KNN) {
                    out1[pos] = t * 64 + lane;
                    float4 q = pts[t * 64 + lane];
                    ax1 += q.x; ay1 += q.y; az1 += q.z;
                }
                bs += (unsigned)__popcll(mask);
            }
        }
    }

    #pragma unroll
    for (int off = 32; off; off >>= 1) {
        ax0 += __shfl_xor(ax0, off, 64);
        ay0 += __shfl_xor(ay0, off, 64);
        az0 += __shfl_xor(az0, off, 64);
        ax1 += __shfl_xor(ax1, off, 64);
        ay1 += __shfl_xor(ay1, off, 64);
        az1 += __shfl_xor(az1, off, 64);
    }

    // ---- fused layer 1 (both queries; W1 loads amortized) -----------------
    #pragma unroll
    for (int hh = 0; hh < 2; ++hh) {
        int h = lane + hh * 64;
        float w0 = W1r[h * 3 + 0], w1 = W1r[h * 3 + 1], w2 = W1r[h * 3 + 2];
        float s0 = W1s[h * 3 + 0], s1 = W1s[h * 3 + 1], s2 = W1s[h * 3 + 2];
        float bb = b1[h];
        float a0 = bb + w0 * ax0 + w1 * ay0 + w2 * az0
                      + s0 * pi0.x + s1 * pi0.y + s2 * pi0.z;
        float a1 = bb + w0 * ax1 + w1 * ay1 + w2 * az1
                      + s0 * pi1.x + s1 * pi1.y + s2 * pi1.z;
        xst[r0q][h] = f2bf(fmaxf(a0, 0.f));
        xst[r1q][h] = f2bf(fmaxf(a1, 0.f));
    }
    __syncthreads();
    if (threadIdx.x < QPB * 16) {                 // 256 tasks x 16 B
        int pt = threadIdx.x >> 4, cc = threadIdx.x & 15;
        uint4 vv = *(const uint4*)&xst[pt][cc * 8];
        *(uint4*)&x1[((size_t)b * NPTS + rblk * QPB + pt) * HID + cc * 8] = vv;
    }
}

// ---------------------------------------------------------------------------
// Fused gather + GEMM conv (R13/R17 structure, unchanged).
// ---------------------------------------------------------------------------
template <bool RELU, bool OUT_BF16>
__global__ __launch_bounds__(512) void fusedconv_kernel(
    const unsigned short* __restrict__ xR, const int* __restrict__ nbr,
    const unsigned short* __restrict__ wTr, const unsigned short* __restrict__ wTs,
    const float* __restrict__ bias, void* __restrict__ outv)
{
    // union: agg [16][64][8] bf16 (16KB) / epilogue bf16 [64][136] / f32 [64][132]
    __shared__ __align__(16) char smem[64 * 132 * 4];
    unsigned short (*agg)[64][8] = (unsigned short (*)[64][8])smem;
    unsigned short (*obf)[136] = (unsigned short (*)[136])smem;
    float (*of32)[132] = (float (*)[132])smem;

    const int p0 = blockIdx.x * 64;                   // global point base
    const int b = blockIdx.x >> 5;                    // 32 blocks per batch
    const unsigned short* xb = xR + (size_t)b * NPTS * HID;

    // ---- phase 1: neighbor gather into LDS agg tile -----------------------
    {
        const int pt = threadIdx.x >> 3;              // 0..63
        const int sub = threadIdx.x & 7;              // chunk planes sub, sub+8
        const int4* nr4 = (const int4*)(nbr + (size_t)(p0 + pt) * KNN);
        int4 n0 = nr4[0], n1 = nr4[1], n2 = nr4[2], n3 = nr4[3];
        int idx[16] = {n0.x, n0.y, n0.z, n0.w, n1.x, n1.y, n1.z, n1.w,
                       n2.x, n2.y, n2.z, n2.w, n3.x, n3.y, n3.z, n3.w};
        float s0[8] = {0, 0, 0, 0, 0, 0, 0, 0};
        float s1[8] = {0, 0, 0, 0, 0, 0, 0, 0};
        #pragma unroll
        for (int t = 0; t < KNN; ++t) {
            const unsigned short* rowp = xb + (size_t)idx[t] * HID + sub * 8;
            uint4 va = *(const uint4*)rowp;           // plane sub
            uint4 vb = *(const uint4*)(rowp + 64);    // plane sub+8
            s0[0] += bflo(va.x); s0[1] += bfhi(va.x);
            s0[2] += bflo(va.y); s0[3] += bfhi(va.y);
            s0[4] += bflo(va.z); s0[5] += bfhi(va.z);
            s0[6] += bflo(va.w); s0[7] += bfhi(va.w);
            s1[0] += bflo(vb.x); s1[1] += bfhi(vb.x);
            s1[2] += bflo(vb.y); s1[3] += bfhi(vb.y);
            s1[4] += bflo(vb.z); s1[5] += bfhi(vb.z);
            s1[6] += bflo(vb.w); s1[7] += bfhi(vb.w);
        }
        uint4 o0, o1;
        o0.x = (unsigned)f2bf(s0[0]) | ((unsigned)f2bf(s0[1]) << 16);
        o0.y = (unsigned)f2bf(s0[2]) | ((unsigned)f2bf(s0[3]) << 16);
        o0.z = (unsigned)f2bf(s0[4]) | ((unsigned)f2bf(s0[5]) << 16);
        o0.w = (unsigned)f2bf(s0[6]) | ((unsigned)f2bf(s0[7]) << 16);
        o1.x = (unsigned)f2bf(s1[0]) | ((unsigned)f2bf(s1[1]) << 16);
        o1.y = (unsigned)f2bf(s1[2]) | ((unsigned)f2bf(s1[3]) << 16);
        o1.z = (unsigned)f2bf(s1[4]) | ((unsigned)f2bf(s1[5]) << 16);
        o1.w = (unsigned)f2bf(s1[6]) | ((unsigned)f2bf(s1[7]) << 16);
        *(uint4*)agg[sub][pt] = o0;
        *(uint4*)agg[sub + 8][pt] = o1;
    }
    __syncthreads();

    // ---- phase 2: MFMA ----------------------------------------------------
    const int wv = threadIdx.x >> 6;
    const int lane = threadIdx.x & 63;
    const int ptw = (wv & 1) * 32;                // 0 / 32
    const int h0w = (wv >> 1) * 32;               // 0 / 32 / 64 / 96
    const int row = lane & 15;
    const int quad = lane >> 4;

    f32x4 acc[2][2];
    #pragma unroll
    for (int i = 0; i < 2; ++i)
        #pragma unroll
        for (int n = 0; n < 2; ++n) acc[i][n] = (f32x4){0, 0, 0, 0};

    // agg @ Wr^T (A-frags from LDS)
    #pragma unroll
    for (int kc = 0; kc < 4; ++kc) {
        const int pl = quad + 4 * kc;             // chunk plane = k/8
        bf16x8 a0 = *(const bf16x8*)agg[pl][ptw + row];
        bf16x8 a1 = *(const bf16x8*)agg[pl][ptw + 16 + row];
        #pragma unroll
        for (int n = 0; n < 2; ++n) {
            bf16x8 bb = *(const bf16x8*)(wTr + ((size_t)pl * HID + h0w + n * 16 + row) * 8);
            acc[0][n] = __builtin_amdgcn_mfma_f32_16x16x32_bf16(a0, bb, acc[0][n], 0, 0, 0);
            acc[1][n] = __builtin_amdgcn_mfma_f32_16x16x32_bf16(a1, bb, acc[1][n], 0, 0, 0);
        }
    }
    // x @ Ws^T (A-frags from row-major global; kc loop covers full 256B row)
    #pragma unroll
    for (int kc = 0; kc < 4; ++kc) {
        const int pl = quad + 4 * kc;
        bf16x8 a0 = *(const bf16x8*)(xR + (size_t)(p0 + ptw + row) * HID + pl * 8);
        bf16x8 a1 = *(const bf16x8*)(xR + (size_t)(p0 + ptw + 16 + row) * HID + pl * 8);
        #pragma unroll
        for (int n = 0; n < 2; ++n) {
            bf16x8 bb = *(const bf16x8*)(wTs + ((size_t)pl * HID + h0w + n * 16 + row) * 8);
            acc[0][n] = __builtin_amdgcn_mfma_f32_16x16x32_bf16(a0, bb, acc[0][n], 0, 0, 0);
            acc[1][n] = __builtin_amdgcn_mfma_f32_16x16x32_bf16(a1, bb, acc[1][n], 0, 0, 0);
        }
    }
    __syncthreads();    // agg LDS reads complete before epilogue overlay

    // ---- phase 3: epilogue: bias/relu -> LDS tile -> coalesced stores -----
    #pragma unroll
    for (int n = 0; n < 2; ++n) {
        float bh = bias[h0w + n * 16 + row];
        #pragma unroll
        for (int i = 0; i < 2; ++i) {
            #pragma unroll
            for (int r = 0; r < 4; ++r) {
                int pt = ptw + i * 16 + quad * 4 + r;     // 0..63 in tile
                int hh = h0w + n * 16 + row;              // 0..127
                float vv = acc[i][n][r] + bh;
                if (RELU) vv = fmaxf(vv, 0.f);
                if (OUT_BF16) obf[pt][hh] = f2bf(vv);
                else          of32[pt][hh] = vv;
            }
        }
    }
    __syncthreads();

    if (OUT_BF16) {
        unsigned short* o = (unsigned short*)outv;        // row-major bf16
        #pragma unroll
        for (int q = 0; q < 2; ++q) {
            int task = q * 512 + threadIdx.x;     // 1024 = 64 pts x 16 chunks
            int pt = task >> 4, cc = task & 15;
            *(uint4*)(o + (size_t)(p0 + pt) * HID + cc * 8) =
                *(const uint4*)&obf[pt][cc * 8];
        }
    } else {
        float* o = (float*)outv;                          // row-major f32
        #pragma unroll
        for (int q = 0; q < 4; ++q) {
            int task = q * 512 + threadIdx.x;     // 2048 = 64 rows x 32 chunks
            int rr = task >> 5, ch = task & 31;
            *(float4*)(o + (size_t)(p0 + rr) * HID + ch * 4) =
                *(const float4*)&of32[rr][ch * 4];
        }
    }
}

// ---------------------------------------------------------------------------
extern "C" void kernel_launch(void* const* d_in, const int* in_sizes, int n_in,
                              void* d_out, int out_size, void* d_ws, size_t ws_size,
                              hipStream_t stream)
{
    const float* pc  = (const float*)d_in[0];
    const float* W1r = (const float*)d_in[1];
    const float* b1  = (const float*)d_in[2];
    const float* W1s = (const float*)d_in[3];
    const float* W2r = (const float*)d_in[4];
    const float* b2  = (const float*)d_in[5];
    const float* W2s = (const float*)d_in[6];
    const float* W3r = (const float*)d_in[7];
    const float* b3  = (const float*)d_in[8];
    const float* W3s = (const float*)d_in[9];
    float* out = (float*)d_out;

    char* ws = (char*)d_ws;
    const size_t MB = 1024 * 1024;
    const size_t XSZ = (size_t)NPOINTS * HID * 2;                // 8.39 MB
    int*            nbr  = (int*)ws;                             // 2 MB
    unsigned short* x1   = (unsigned short*)(ws + 2 * MB);       // row-major
    unsigned short* x2   = (unsigned short*)(ws + 2 * MB + XSZ); // row-major
    unsigned short* wT   = (unsigned short*)(ws + 2 * MB + 2 * XSZ);
    unsigned short* w2rT = wT;
    unsigned short* w2sT = wT + 16384;
    unsigned short* w3rT = wT + 32768;
    unsigned short* w3sT = wT + 49152;

    // launch 1: kNN + fused layer 1 (+32 trailing blocks do weight cvt)
    knn_kernel<<<KNN_BLOCKS + 32, 512, 0, stream>>>(
        pc, nbr, W1r, b1, W1s, x1, W2r, W2s, W3r, W3s, wT);

    // launch 2: fused gather+conv2 -> x2 (row-major bf16, relu)
    fusedconv_kernel<true, true><<<NPOINTS / 64, 512, 0, stream>>>(
        x1, nbr, w2rT, w2sT, b2, x2);

    // launch 3: fused gather+conv3 -> out (row-major f32)
    fusedconv_kernel<false, false><<<NPOINTS / 64, 512, 0, stream>>>(
        x2, nbr, w3rT, w3sT, b3, out);
}

// Round 10
// 171.008 us; speedup vs baseline: 1.0945x; 1.0945x over previous
//
#include <hip/hip_runtime.h>
#include <math.h>

#define NPTS 2048
#define BATCH 16
#define KNN 16
#define HID 128
#define NPOINTS (BATCH * NPTS)   // 32768
#define QPB 16         // queries per block = waves per block (1024 threads)
#define CAP 64         // compacted-candidate capacity per query (m ~ 18.4 avg)
#define KNN_BLOCKS (NPOINTS / QPB)   // 2048

typedef __attribute__((ext_vector_type(8))) short bf16x8;
typedef __attribute__((ext_vector_type(4))) float f32x4;

__device__ inline unsigned short f2bf(float f) {    // RNE f32 -> bf16 bits
    unsigned u = __float_as_uint(f);
    return (unsigned short)((u + 0x7FFFu + ((u >> 16) & 1u)) >> 16);
}
__device__ inline float bflo(unsigned v) { return __uint_as_float(v << 16); }
__device__ inline float bfhi(unsigned v) { return __uint_as_float(v & 0xFFFF0000u); }

// x1/x2 ROW-MAJOR bf16 [32768][128]; weights chunked-T (wT[cc][h][8]).
//
// R19: R18's 2-queries/wave REVERTED -- VGPR 36->76 crossed the 64-reg
// occupancy cliff (8->4 waves/SIMD), knn doubled. Ledger: never trade
// VGPR past 64 in this kernel. This round: R17 selection code verbatim
// (VGPR ~36), but 1024-thread blocks = 16 queries/block so the 32KB pts
// staging amortizes over 2x queries (2048 blocks). LDS 44KB; residency is
// wave-capped at 2 blocks x 16 waves = 32/CU = same 100% ceiling as R17.
// Budget: harness reset ~107us (not addressable) + knn ~42 + convs ~8.

// ---------------------------------------------------------------------------
// kNN + fused layer 1. One wave per query row, 16 rows per block.
// ---------------------------------------------------------------------------
__global__ __launch_bounds__(1024) void knn_kernel(
    const float* __restrict__ pc, int* __restrict__ nbr,
    const float* __restrict__ W1r, const float* __restrict__ b1,
    const float* __restrict__ W1s, unsigned short* __restrict__ x1,
    const float* __restrict__ W2r, const float* __restrict__ W2s,
    const float* __restrict__ W3r, const float* __restrict__ W3s,
    unsigned short* __restrict__ wT)
{
    __shared__ __align__(16) float4 pts[NPTS];              // 32 KB
    __shared__ unsigned ckey[QPB][CAP];                     // 4 KB
    __shared__ unsigned cidx[QPB][CAP];                     // 4 KB
    __shared__ __align__(16) unsigned short xst[QPB][HID];  // 4 KB

    if (blockIdx.x >= KNN_BLOCKS) {
        // ---- folded weight conversion: 32 blocks x 1024 thr x 2 elems -----
        int g = (blockIdx.x - KNN_BLOCKS) * 2048 + (int)threadIdx.x * 2;
        #pragma unroll
        for (int u = 0; u < 2; ++u) {
            int g2 = g + u;
            int mm = g2 >> 14;
            int e = g2 & 16383;
            int r = e >> 7, cch = e & 127;
            const float* s = (mm == 0) ? W2r : (mm == 1) ? W2s
                           : (mm == 2) ? W3r : W3s;
            wT[mm * 16384 + ((cch >> 3) * 128 + r) * 8 + (cch & 7)] = f2bf(s[e]);
        }
        return;
    }

    const int b = blockIdx.x >> 7;                    // 128 blocks per batch
    const int rblk = blockIdx.x & 127;
    const float* p = pc + (size_t)b * NPTS * 3;

    #pragma unroll
    for (int rr = 0; rr < 2; ++rr) {
        int t = rr * 1024 + (int)threadIdx.x;
        float x = p[t * 3 + 0], y = p[t * 3 + 1], z = p[t * 3 + 2];
        pts[t] = make_float4(x, y, z, x * x + y * y + z * z);
    }
    __syncthreads();

    const int w = threadIdx.x >> 6;                   // 0..15
    const int lane = threadIdx.x & 63;
    const int i = rblk * QPB + w;                     // query row in batch
    const float4 pi = pts[i];
    const float piw16 = pi.w + 16.0f;

    unsigned key[32];                                 // STATIC indexing only!
    unsigned km = 0xFFFFFFFFu;
    #pragma unroll
    for (int t = 0; t < 32; ++t) {
        float4 c = pts[t * 64 + lane];
        float dot = fmaf(pi.x, c.x, fmaf(pi.y, c.y, pi.z * c.z));
        float d2 = fmaf(-2.0f, dot, piw16 + c.w);
        key[t] = __float_as_uint(d2);
        km = min(km, key[t]);
    }

    // ---- T0 = 16th-smallest of the 64 per-lane minima (bitonic, parallel) -
    unsigned v = km;
    #pragma unroll
    for (int k = 2; k <= 64; k <<= 1) {
        #pragma unroll
        for (int j = k >> 1; j > 0; j >>= 1) {
            unsigned o = (unsigned)__shfl_xor((int)v, j, 64);
            bool sel = ((lane & k) == 0) == ((lane & j) == 0);
            v = sel ? min(v, o) : max(v, o);
        }
    }
    const unsigned T0 = (unsigned)__shfl((int)v, 15, 64);
    // >=16 candidates <= T0 and T0 >= true 16th => superset of the top-16.

    // ---- compaction: FULLY UNROLLED so key[t] stays in registers ----------
    unsigned base = 0;
    #pragma unroll
    for (int t = 0; t < 32; ++t) {
        bool pred = key[t] <= T0;
        unsigned long long mask = __ballot(pred);
        if (mask) {
            unsigned prefix = __builtin_amdgcn_mbcnt_hi(
                (unsigned)(mask >> 32),
                __builtin_amdgcn_mbcnt_lo((unsigned)mask, 0));
            unsigned pos = base + prefix;
            if (pred && pos < CAP) {
                ckey[w][pos] = key[t];
                cidx[w][pos] = (unsigned)(t * 64 + lane);
            }
            base += (unsigned)__popcll(mask);
        }
    }
    const int m = (int)base;

    int* out = nbr + ((size_t)b * NPTS + i) * KNN;
    float ax = 0.f, ay = 0.f, az = 0.f;               // fused position sum

    if (m <= CAP) {
        unsigned k0 = (lane < m) ? ckey[w][lane] : 0xFFFFFFFFu;
        int r0 = 0;
        #pragma unroll 2
        for (int jj = 0; jj < m; ++jj) {
            unsigned kj = ckey[w][jj];
            r0 += (kj < k0) || (kj == k0 && jj < lane);
        }
        if (lane < m && r0 < KNN) {
            unsigned j = cidx[w][lane];
            out[r0] = (int)j;
            float4 q = pts[j]; ax += q.x; ay += q.y; az += q.z;
        }
    } else {
        // exact fallback (never taken w/ random data; correctness only).
        // Recomputes d2 from LDS pts (same fmaf sequence -> identical bits)
        // so it never runtime-indexes key[] (which would force scratch).
        auto keyat = [&](int t) -> unsigned {
            float4 c = pts[t * 64 + lane];
            float dot = fmaf(pi.x, c.x, fmaf(pi.y, c.y, pi.z * c.z));
            float d2 = fmaf(-2.0f, dot, piw16 + c.w);
            return __float_as_uint(d2);
        };
        unsigned T = 0;
        #pragma unroll 1
        for (int bit = 31; bit >= 0; --bit) {
            unsigned trial = T | (1u << bit);
            int cnt = 0;
            #pragma unroll 1
            for (int t = 0; t < 32; ++t) cnt += (keyat(t) < trial);
            #pragma unroll
            for (int off = 32; off; off >>= 1)
                cnt += __shfl_xor(cnt, off, 64);
            if (cnt < KNN) T = trial;
        }
        unsigned bs = 0;
        #pragma unroll 1
        for (int t = 0; t < 32; ++t) {
            bool p1 = keyat(t) < T;
            unsigned long long mask = __ballot(p1);
            if (mask) {
                unsigned prefix = __builtin_amdgcn_mbcnt_hi(
                    (unsigned)(mask >> 32),
                    __builtin_amdgcn_mbcnt_lo((unsigned)mask, 0));
                if (p1) {
                    out[bs + prefix] = t * 64 + lane;
                    float4 q = pts[t * 64 + lane];
                    ax += q.x; ay += q.y; az += q.z;
                }
                bs += (unsigned)__popcll(mask);
            }
        }
        #pragma unroll 1
        for (int t = 0; t < 32 && bs < KNN; ++t) {
            bool p2 = keyat(t) == T;
            unsigned long long mask = __ballot(p2);
            if (mask) {
                unsigned prefix = __builtin_amdgcn_mbcnt_hi(
                    (unsigned)(mask >> 32),
                    __builtin_amdgcn_mbcnt_lo((unsigned)mask, 0));
                unsigned pos = bs + prefix;
                if (p2 && pos < KNN) {
                    out[pos] = t * 64 + lane;
                    float4 q = pts[t * 64 + lane];
                    ax += q.x; ay += q.y; az += q.z;
                }
                bs += (unsigned)__popcll(mask);
            }
        }
    }

    #pragma unroll
    for (int off = 32; off; off >>= 1) {
        ax += __shfl_xor(ax, off, 64);
        ay += __shfl_xor(ay, off, 64);
        az += __shfl_xor(az, off, 64);
    }

    // ---- fused layer 1 -> LDS stage -> row-major write --------------------
    #pragma unroll
    for (int hh = 0; hh < 2; ++hh) {
        int h = lane + hh * 64;
        float acc = b1[h];
        acc += W1r[h * 3 + 0] * ax + W1r[h * 3 + 1] * ay + W1r[h * 3 + 2] * az;
        acc += W1s[h * 3 + 0] * pi.x + W1s[h * 3 + 1] * pi.y + W1s[h * 3 + 2] * pi.z;
        xst[w][h] = f2bf(fmaxf(acc, 0.f));
    }
    __syncthreads();
    if (threadIdx.x < QPB * 16) {                 // 256 tasks x 16 B
        int pt = threadIdx.x >> 4, cc = threadIdx.x & 15;
        uint4 vv = *(const uint4*)&xst[pt][cc * 8];
        *(uint4*)&x1[((size_t)b * NPTS + rblk * QPB + pt) * HID + cc * 8] = vv;
    }
}

// ---------------------------------------------------------------------------
// Fused gather + GEMM conv (R13/R17 structure, unchanged).
// ---------------------------------------------------------------------------
template <bool RELU, bool OUT_BF16>
__global__ __launch_bounds__(512) void fusedconv_kernel(
    const unsigned short* __restrict__ xR, const int* __restrict__ nbr,
    const unsigned short* __restrict__ wTr, const unsigned short* __restrict__ wTs,
    const float* __restrict__ bias, void* __restrict__ outv)
{
    // union: agg [16][64][8] bf16 (16KB) / epilogue bf16 [64][136] / f32 [64][132]
    __shared__ __align__(16) char smem[64 * 132 * 4];
    unsigned short (*agg)[64][8] = (unsigned short (*)[64][8])smem;
    unsigned short (*obf)[136] = (unsigned short (*)[136])smem;
    float (*of32)[132] = (float (*)[132])smem;

    const int p0 = blockIdx.x * 64;                   // global point base
    const int b = blockIdx.x >> 5;                    // 32 blocks per batch
    const unsigned short* xb = xR + (size_t)b * NPTS * HID;

    // ---- phase 1: neighbor gather into LDS agg tile -----------------------
    {
        const int pt = threadIdx.x >> 3;              // 0..63
        const int sub = threadIdx.x & 7;              // chunk planes sub, sub+8
        const int4* nr4 = (const int4*)(nbr + (size_t)(p0 + pt) * KNN);
        int4 n0 = nr4[0], n1 = nr4[1], n2 = nr4[2], n3 = nr4[3];
        int idx[16] = {n0.x, n0.y, n0.z, n0.w, n1.x, n1.y, n1.z, n1.w,
                       n2.x, n2.y, n2.z, n2.w, n3.x, n3.y, n3.z, n3.w};
        float s0[8] = {0, 0, 0, 0, 0, 0, 0, 0};
        float s1[8] = {0, 0, 0, 0, 0, 0, 0, 0};
        #pragma unroll
        for (int t = 0; t < KNN; ++t) {
            const unsigned short* rowp = xb + (size_t)idx[t] * HID + sub * 8;
            uint4 va = *(const uint4*)rowp;           // plane sub
            uint4 vb = *(const uint4*)(rowp + 64);    // plane sub+8
            s0[0] += bflo(va.x); s0[1] += bfhi(va.x);
            s0[2] += bflo(va.y); s0[3] += bfhi(va.y);
            s0[4] += bflo(va.z); s0[5] += bfhi(va.z);
            s0[6] += bflo(va.w); s0[7] += bfhi(va.w);
            s1[0] += bflo(vb.x); s1[1] += bfhi(vb.x);
            s1[2] += bflo(vb.y); s1[3] += bfhi(vb.y);
            s1[4] += bflo(vb.z); s1[5] += bfhi(vb.z);
            s1[6] += bflo(vb.w); s1[7] += bfhi(vb.w);
        }
        uint4 o0, o1;
        o0.x = (unsigned)f2bf(s0[0]) | ((unsigned)f2bf(s0[1]) << 16);
        o0.y = (unsigned)f2bf(s0[2]) | ((unsigned)f2bf(s0[3]) << 16);
        o0.z = (unsigned)f2bf(s0[4]) | ((unsigned)f2bf(s0[5]) << 16);
        o0.w = (unsigned)f2bf(s0[6]) | ((unsigned)f2bf(s0[7]) << 16);
        o1.x = (unsigned)f2bf(s1[0]) | ((unsigned)f2bf(s1[1]) << 16);
        o1.y = (unsigned)f2bf(s1[2]) | ((unsigned)f2bf(s1[3]) << 16);
        o1.z = (unsigned)f2bf(s1[4]) | ((unsigned)f2bf(s1[5]) << 16);
        o1.w = (unsigned)f2bf(s1[6]) | ((unsigned)f2bf(s1[7]) << 16);
        *(uint4*)agg[sub][pt] = o0;
        *(uint4*)agg[sub + 8][pt] = o1;
    }
    __syncthreads();

    // ---- phase 2: MFMA ----------------------------------------------------
    const int wv = threadIdx.x >> 6;
    const int lane = threadIdx.x & 63;
    const int ptw = (wv & 1) * 32;                // 0 / 32
    const int h0w = (wv >> 1) * 32;               // 0 / 32 / 64 / 96
    const int row = lane & 15;
    const int quad = lane >> 4;

    f32x4 acc[2][2];
    #pragma unroll
    for (int i = 0; i < 2; ++i)
        #pragma unroll
        for (int n = 0; n < 2; ++n) acc[i][n] = (f32x4){0, 0, 0, 0};

    // agg @ Wr^T (A-frags from LDS)
    #pragma unroll
    for (int kc = 0; kc < 4; ++kc) {
        const int pl = quad + 4 * kc;             // chunk plane = k/8
        bf16x8 a0 = *(const bf16x8*)agg[pl][ptw + row];
        bf16x8 a1 = *(const bf16x8*)agg[pl][ptw + 16 + row];
        #pragma unroll
        for (int n = 0; n < 2; ++n) {
            bf16x8 bb = *(const bf16x8*)(wTr + ((size_t)pl * HID + h0w + n * 16 + row) * 8);
            acc[0][n] = __builtin_amdgcn_mfma_f32_16x16x32_bf16(a0, bb, acc[0][n], 0, 0, 0);
            acc[1][n] = __builtin_amdgcn_mfma_f32_16x16x32_bf16(a1, bb, acc[1][n], 0, 0, 0);
        }
    }
    // x @ Ws^T (A-frags from row-major global; kc loop covers full 256B row)
    #pragma unroll
    for (int kc = 0; kc < 4; ++kc) {
        const int pl = quad + 4 * kc;
        bf16x8 a0 = *(const bf16x8*)(xR + (size_t)(p0 + ptw + row) * HID + pl * 8);
        bf16x8 a1 = *(const bf16x8*)(xR + (size_t)(p0 + ptw + 16 + row) * HID + pl * 8);
        #pragma unroll
        for (int n = 0; n < 2; ++n) {
            bf16x8 bb = *(const bf16x8*)(wTs + ((size_t)pl * HID + h0w + n * 16 + row) * 8);
            acc[0][n] = __builtin_amdgcn_mfma_f32_16x16x32_bf16(a0, bb, acc[0][n], 0, 0, 0);
            acc[1][n] = __builtin_amdgcn_mfma_f32_16x16x32_bf16(a1, bb, acc[1][n], 0, 0, 0);
        }
    }
    __syncthreads();    // agg LDS reads complete before epilogue overlay

    // ---- phase 3: epilogue: bias/relu -> LDS tile -> coalesced stores -----
    #pragma unroll
    for (int n = 0; n < 2; ++n) {
        float bh = bias[h0w + n * 16 + row];
        #pragma unroll
        for (int i = 0; i < 2; ++i) {
            #pragma unroll
            for (int r = 0; r < 4; ++r) {
                int pt = ptw + i * 16 + quad * 4 + r;     // 0..63 in tile
                int hh = h0w + n * 16 + row;              // 0..127
                float vv = acc[i][n][r] + bh;
                if (RELU) vv = fmaxf(vv, 0.f);
                if (OUT_BF16) obf[pt][hh] = f2bf(vv);
                else          of32[pt][hh] = vv;
            }
        }
    }
    __syncthreads();

    if (OUT_BF16) {
        unsigned short* o = (unsigned short*)outv;        // row-major bf16
        #pragma unroll
        for (int q = 0; q < 2; ++q) {
            int task = q * 512 + threadIdx.x;     // 1024 = 64 pts x 16 chunks
            int pt = task >> 4, cc = task & 15;
            *(uint4*)(o + (size_t)(p0 + pt) * HID + cc * 8) =
                *(const uint4*)&obf[pt][cc * 8];
        }
    } else {
        float* o = (float*)outv;                          // row-major f32
        #pragma unroll
        for (int q = 0; q < 4; ++q) {
            int task = q * 512 + threadIdx.x;     // 2048 = 64 rows x 32 chunks
            int rr = task >> 5, ch = task & 31;
            *(float4*)(o + (size_t)(p0 + rr) * HID + ch * 4) =
                *(const float4*)&of32[rr][ch * 4];
        }
    }
}

// ---------------------------------------------------------------------------
extern "C" void kernel_launch(void* const* d_in, const int* in_sizes, int n_in,
                              void* d_out, int out_size, void* d_ws, size_t ws_size,
                              hipStream_t stream)
{
    const float* pc  = (const float*)d_in[0];
    const float* W1r = (const float*)d_in[1];
    const float* b1  = (const float*)d_in[2];
    const float* W1s = (const float*)d_in[3];
    const float* W2r = (const float*)d_in[4];
    const float* b2  = (const float*)d_in[5];
    const float* W2s = (const float*)d_in[6];
    const float* W3r = (const float*)d_in[7];
    const float* b3  = (const float*)d_in[8];
    const float* W3s = (const float*)d_in[9];
    float* out = (float*)d_out;

    char* ws = (char*)d_ws;
    const size_t MB = 1024 * 1024;
    const size_t XSZ = (size_t)NPOINTS * HID * 2;                // 8.39 MB
    int*            nbr  = (int*)ws;                             // 2 MB
    unsigned short* x1   = (unsigned short*)(ws + 2 * MB);       // row-major
    unsigned short* x2   = (unsigned short*)(ws + 2 * MB + XSZ); // row-major
    unsigned short* wT   = (unsigned short*)(ws + 2 * MB + 2 * XSZ);
    unsigned short* w2rT = wT;
    unsigned short* w2sT = wT + 16384;
    unsigned short* w3rT = wT + 32768;
    unsigned short* w3sT = wT + 49152;

    // launch 1: kNN + fused layer 1 (+32 trailing blocks do weight cvt)
    knn_kernel<<<KNN_BLOCKS + 32, 1024, 0, stream>>>(
        pc, nbr, W1r, b1, W1s, x1, W2r, W2s, W3r, W3s, wT);

    // launch 2: fused gather+conv2 -> x2 (row-major bf16, relu)
    fusedconv_kernel<true, true><<<NPOINTS / 64, 512, 0, stream>>>(
        x1, nbr, w2rT, w2sT, b2, x2);

    // launch 3: fused gather+conv3 -> out (row-major f32)
    fusedconv_kernel<false, false><<<NPOINTS / 64, 512, 0, stream>>>(
        x2, nbr, w3rT, w3sT, b3, out);
}

// Round 11
// 170.228 us; speedup vs baseline: 1.0995x; 1.0046x over previous
//
#include <hip/hip_runtime.h>
#include <math.h>

#define NPTS 2048
#define BATCH 16
#define KNN 16
#define HID 128
#define NPOINTS (BATCH * NPTS)   // 32768
#define RPB 8          // rows (queries) per block = waves per block
#define CAP 64         // compacted-candidate capacity per query (m ~ 18.4 avg)
#define KNN_BLOCKS (NPOINTS / RPB)   // 4096

typedef __attribute__((ext_vector_type(8))) short bf16x8;
typedef __attribute__((ext_vector_type(4))) float f32x4;

__device__ inline unsigned short f2bf(float f) {    // RNE f32 -> bf16 bits
    unsigned u = __float_as_uint(f);
    return (unsigned short)((u + 0x7FFFu + ((u >> 16) & 1u)) >> 16);
}
__device__ inline float bflo(unsigned v) { return __uint_as_float(v << 16); }
__device__ inline float bfhi(unsigned v) { return __uint_as_float(v & 0xFFFF0000u); }

// x1/x2 ROW-MAJOR bf16 [32768][128]; weights chunked-T (wT[cc][h][8]).
//
// R20: R19's 1024-thread block REVERTED (occupancy granularity loss: knn
// 42->63us; ledger: keep 512-thr/8-wave blocks). R17 structure + ONE change:
// compaction packs (key<<32|idx) into a single u64 cand[] -- one ds_write_b64
// per hit-iteration instead of two ds_write_b32; rank loop reads/compares
// u64 (unique => no tie-break); emit extracts idx from the register.
// Cuts the compaction+rank DS share (~25% of knn's ~1000 DS-cyc/wave).
// Budget: harness reset ~107us (not addressable) + knn ~42 + convs ~8.

// ---------------------------------------------------------------------------
// kNN + fused layer 1. One wave per query row.
// ---------------------------------------------------------------------------
__global__ __launch_bounds__(512) void knn_kernel(
    const float* __restrict__ pc, int* __restrict__ nbr,
    const float* __restrict__ W1r, const float* __restrict__ b1,
    const float* __restrict__ W1s, unsigned short* __restrict__ x1,
    const float* __restrict__ W2r, const float* __restrict__ W2s,
    const float* __restrict__ W3r, const float* __restrict__ W3s,
    unsigned short* __restrict__ wT)
{
    __shared__ __align__(16) float4 pts[NPTS];              // 32 KB
    __shared__ unsigned long long cand[RPB][CAP];           // 4 KB
    __shared__ __align__(16) unsigned short xst[RPB][HID];  // 2 KB

    if (blockIdx.x >= KNN_BLOCKS) {
        // ---- folded weight conversion: 32 blocks x 512 thr x 4 elems ------
        int g = (blockIdx.x - KNN_BLOCKS) * 2048 + (int)threadIdx.x * 4;
        #pragma unroll
        for (int u = 0; u < 4; ++u) {
            int g2 = g + u;
            int mm = g2 >> 14;
            int e = g2 & 16383;
            int r = e >> 7, cch = e & 127;
            const float* s = (mm == 0) ? W2r : (mm == 1) ? W2s
                           : (mm == 2) ? W3r : W3s;
            wT[mm * 16384 + ((cch >> 3) * 128 + r) * 8 + (cch & 7)] = f2bf(s[e]);
        }
        return;
    }

    const int b = blockIdx.x >> 8;                    // 256 blocks per batch
    const int rblk = blockIdx.x & 255;
    const float* p = pc + (size_t)b * NPTS * 3;

    for (int t = threadIdx.x; t < NPTS; t += 512) {
        float x = p[t * 3 + 0], y = p[t * 3 + 1], z = p[t * 3 + 2];
        pts[t] = make_float4(x, y, z, x * x + y * y + z * z);
    }
    __syncthreads();

    const int w = threadIdx.x >> 6;
    const int lane = threadIdx.x & 63;
    const int i = rblk * RPB + w;                     // query row in batch
    const float4 pi = pts[i];
    const float piw16 = pi.w + 16.0f;

    unsigned key[32];                                 // STATIC indexing only!
    unsigned km = 0xFFFFFFFFu;
    #pragma unroll
    for (int t = 0; t < 32; ++t) {
        float4 c = pts[t * 64 + lane];
        float dot = fmaf(pi.x, c.x, fmaf(pi.y, c.y, pi.z * c.z));
        float d2 = fmaf(-2.0f, dot, piw16 + c.w);
        key[t] = __float_as_uint(d2);
        km = min(km, key[t]);
    }

    // ---- T0 = 16th-smallest of the 64 per-lane minima (bitonic, parallel) -
    unsigned v = km;
    #pragma unroll
    for (int k = 2; k <= 64; k <<= 1) {
        #pragma unroll
        for (int j = k >> 1; j > 0; j >>= 1) {
            unsigned o = (unsigned)__shfl_xor((int)v, j, 64);
            bool sel = ((lane & k) == 0) == ((lane & j) == 0);
            v = sel ? min(v, o) : max(v, o);
        }
    }
    const unsigned T0 = (unsigned)__shfl((int)v, 15, 64);
    // >=16 candidates <= T0 and T0 >= true 16th => superset of the top-16.

    // ---- compaction: fully unrolled, packed u64 = key<<32|idx -------------
    unsigned base = 0;
    #pragma unroll
    for (int t = 0; t < 32; ++t) {
        bool pred = key[t] <= T0;
        unsigned long long mask = __ballot(pred);
        if (mask) {
            unsigned prefix = __builtin_amdgcn_mbcnt_hi(
                (unsigned)(mask >> 32),
                __builtin_amdgcn_mbcnt_lo((unsigned)mask, 0));
            unsigned pos = base + prefix;
            if (pred && pos < CAP)
                cand[w][pos] = ((unsigned long long)key[t] << 32)
                             | (unsigned)(t * 64 + lane);
            base += (unsigned)__popcll(mask);
        }
    }
    const int m = (int)base;

    int* out = nbr + ((size_t)b * NPTS + i) * KNN;
    float ax = 0.f, ay = 0.f, az = 0.f;               // fused position sum

    if (m <= CAP) {
        // one b64 read/lane + m broadcast b64 reads; u64s distinct (idx
        // unique in low bits) => strict < is a total order, no tie-break.
        unsigned long long c0 = (lane < m) ? cand[w][lane] : ~0ULL;
        int r0 = 0;
        #pragma unroll 4
        for (int jj = 0; jj < m; ++jj)
            r0 += (cand[w][jj] < c0);
        if (lane < m && r0 < KNN) {
            unsigned j = (unsigned)c0;
            out[r0] = (int)j;
            float4 q = pts[j]; ax += q.x; ay += q.y; az += q.z;
        }
    } else {
        // exact fallback (never taken w/ random data; correctness only).
        // Recomputes d2 from LDS pts (same fmaf sequence -> identical bits)
        // so it never runtime-indexes key[] (which would force scratch).
        auto keyat = [&](int t) -> unsigned {
            float4 c = pts[t * 64 + lane];
            float dot = fmaf(pi.x, c.x, fmaf(pi.y, c.y, pi.z * c.z));
            float d2 = fmaf(-2.0f, dot, piw16 + c.w);
            return __float_as_uint(d2);
        };
        unsigned T = 0;
        #pragma unroll 1
        for (int bit = 31; bit >= 0; --bit) {
            unsigned trial = T | (1u << bit);
            int cnt = 0;
            #pragma unroll 1
            for (int t = 0; t < 32; ++t) cnt += (keyat(t) < trial);
            #pragma unroll
            for (int off = 32; off; off >>= 1)
                cnt += __shfl_xor(cnt, off, 64);
            if (cnt < KNN) T = trial;
        }
        unsigned bs = 0;
        #pragma unroll 1
        for (int t = 0; t < 32; ++t) {
            bool p1 = keyat(t) < T;
            unsigned long long mask = __ballot(p1);
            if (mask) {
                unsigned prefix = __builtin_amdgcn_mbcnt_hi(
                    (unsigned)(mask >> 32),
                    __builtin_amdgcn_mbcnt_lo((unsigned)mask, 0));
                if (p1) {
                    out[bs + prefix] = t * 64 + lane;
                    float4 q = pts[t * 64 + lane];
                    ax += q.x; ay += q.y; az += q.z;
                }
                bs += (unsigned)__popcll(mask);
            }
        }
        #pragma unroll 1
        for (int t = 0; t < 32 && bs < KNN; ++t) {
            bool p2 = keyat(t) == T;
            unsigned long long mask = __ballot(p2);
            if (mask) {
                unsigned prefix = __builtin_amdgcn_mbcnt_hi(
                    (unsigned)(mask >> 32),
                    __builtin_amdgcn_mbcnt_lo((unsigned)mask, 0));
                unsigned pos = bs + prefix;
                if (p2 && pos < KNN) {
                    out[pos] = t * 64 + lane;
                    float4 q = pts[t * 64 + lane];
                    ax += q.x; ay += q.y; az += q.z;
                }
                bs += (unsigned)__popcll(mask);
            }
        }
    }

    #pragma unroll
    for (int off = 32; off; off >>= 1) {
        ax += __shfl_xor(ax, off, 64);
        ay += __shfl_xor(ay, off, 64);
        az += __shfl_xor(az, off, 64);
    }

    // ---- fused layer 1 -> LDS stage -> row-major write --------------------
    #pragma unroll
    for (int hh = 0; hh < 2; ++hh) {
        int h = lane + hh * 64;
        float acc = b1[h];
        acc += W1r[h * 3 + 0] * ax + W1r[h * 3 + 1] * ay + W1r[h * 3 + 2] * az;
        acc += W1s[h * 3 + 0] * pi.x + W1s[h * 3 + 1] * pi.y + W1s[h * 3 + 2] * pi.z;
        xst[w][h] = f2bf(fmaxf(acc, 0.f));
    }
    __syncthreads();
    if (threadIdx.x < RPB * 16) {                 // 128 tasks x 16 B
        int pt = threadIdx.x >> 4, cc = threadIdx.x & 15;
        uint4 vv = *(const uint4*)&xst[pt][cc * 8];
        *(uint4*)&x1[((size_t)b * NPTS + rblk * RPB + pt) * HID + cc * 8] = vv;
    }
}

// ---------------------------------------------------------------------------
// Fused gather + GEMM conv (R13/R17 structure, unchanged).
// ---------------------------------------------------------------------------
template <bool RELU, bool OUT_BF16>
__global__ __launch_bounds__(512) void fusedconv_kernel(
    const unsigned short* __restrict__ xR, const int* __restrict__ nbr,
    const unsigned short* __restrict__ wTr, const unsigned short* __restrict__ wTs,
    const float* __restrict__ bias, void* __restrict__ outv)
{
    // union: agg [16][64][8] bf16 (16KB) / epilogue bf16 [64][136] / f32 [64][132]
    __shared__ __align__(16) char smem[64 * 132 * 4];
    unsigned short (*agg)[64][8] = (unsigned short (*)[64][8])smem;
    unsigned short (*obf)[136] = (unsigned short (*)[136])smem;
    float (*of32)[132] = (float (*)[132])smem;

    const int p0 = blockIdx.x * 64;                   // global point base
    const int b = blockIdx.x >> 5;                    // 32 blocks per batch
    const unsigned short* xb = xR + (size_t)b * NPTS * HID;

    // ---- phase 1: neighbor gather into LDS agg tile -----------------------
    {
        const int pt = threadIdx.x >> 3;              // 0..63
        const int sub = threadIdx.x & 7;              // chunk planes sub, sub+8
        const int4* nr4 = (const int4*)(nbr + (size_t)(p0 + pt) * KNN);
        int4 n0 = nr4[0], n1 = nr4[1], n2 = nr4[2], n3 = nr4[3];
        int idx[16] = {n0.x, n0.y, n0.z, n0.w, n1.x, n1.y, n1.z, n1.w,
                       n2.x, n2.y, n2.z, n2.w, n3.x, n3.y, n3.z, n3.w};
        float s0[8] = {0, 0, 0, 0, 0, 0, 0, 0};
        float s1[8] = {0, 0, 0, 0, 0, 0, 0, 0};
        #pragma unroll
        for (int t = 0; t < KNN; ++t) {
            const unsigned short* rowp = xb + (size_t)idx[t] * HID + sub * 8;
            uint4 va = *(const uint4*)rowp;           // plane sub
            uint4 vb = *(const uint4*)(rowp + 64);    // plane sub+8
            s0[0] += bflo(va.x); s0[1] += bfhi(va.x);
            s0[2] += bflo(va.y); s0[3] += bfhi(va.y);
            s0[4] += bflo(va.z); s0[5] += bfhi(va.z);
            s0[6] += bflo(va.w); s0[7] += bfhi(va.w);
            s1[0] += bflo(vb.x); s1[1] += bfhi(vb.x);
            s1[2] += bflo(vb.y); s1[3] += bfhi(vb.y);
            s1[4] += bflo(vb.z); s1[5] += bfhi(vb.z);
            s1[6] += bflo(vb.w); s1[7] += bfhi(vb.w);
        }
        uint4 o0, o1;
        o0.x = (unsigned)f2bf(s0[0]) | ((unsigned)f2bf(s0[1]) << 16);
        o0.y = (unsigned)f2bf(s0[2]) | ((unsigned)f2bf(s0[3]) << 16);
        o0.z = (unsigned)f2bf(s0[4]) | ((unsigned)f2bf(s0[5]) << 16);
        o0.w = (unsigned)f2bf(s0[6]) | ((unsigned)f2bf(s0[7]) << 16);
        o1.x = (unsigned)f2bf(s1[0]) | ((unsigned)f2bf(s1[1]) << 16);
        o1.y = (unsigned)f2bf(s1[2]) | ((unsigned)f2bf(s1[3]) << 16);
        o1.z = (unsigned)f2bf(s1[4]) | ((unsigned)f2bf(s1[5]) << 16);
        o1.w = (unsigned)f2bf(s1[6]) | ((unsigned)f2bf(s1[7]) << 16);
        *(uint4*)agg[sub][pt] = o0;
        *(uint4*)agg[sub + 8][pt] = o1;
    }
    __syncthreads();

    // ---- phase 2: MFMA ----------------------------------------------------
    const int wv = threadIdx.x >> 6;
    const int lane = threadIdx.x & 63;
    const int ptw = (wv & 1) * 32;                // 0 / 32
    const int h0w = (wv >> 1) * 32;               // 0 / 32 / 64 / 96
    const int row = lane & 15;
    const int quad = lane >> 4;

    f32x4 acc[2][2];
    #pragma unroll
    for (int i = 0; i < 2; ++i)
        #pragma unroll
        for (int n = 0; n < 2; ++n) acc[i][n] = (f32x4){0, 0, 0, 0};

    // agg @ Wr^T (A-frags from LDS)
    #pragma unroll
    for (int kc = 0; kc < 4; ++kc) {
        const int pl = quad + 4 * kc;             // chunk plane = k/8
        bf16x8 a0 = *(const bf16x8*)agg[pl][ptw + row];
        bf16x8 a1 = *(const bf16x8*)agg[pl][ptw + 16 + row];
        #pragma unroll
        for (int n = 0; n < 2; ++n) {
            bf16x8 bb = *(const bf16x8*)(wTr + ((size_t)pl * HID + h0w + n * 16 + row) * 8);
            acc[0][n] = __builtin_amdgcn_mfma_f32_16x16x32_bf16(a0, bb, acc[0][n], 0, 0, 0);
            acc[1][n] = __builtin_amdgcn_mfma_f32_16x16x32_bf16(a1, bb, acc[1][n], 0, 0, 0);
        }
    }
    // x @ Ws^T (A-frags from row-major global; kc loop covers full 256B row)
    #pragma unroll
    for (int kc = 0; kc < 4; ++kc) {
        const int pl = quad + 4 * kc;
        bf16x8 a0 = *(const bf16x8*)(xR + (size_t)(p0 + ptw + row) * HID + pl * 8);
        bf16x8 a1 = *(const bf16x8*)(xR + (size_t)(p0 + ptw + 16 + row) * HID + pl * 8);
        #pragma unroll
        for (int n = 0; n < 2; ++n) {
            bf16x8 bb = *(const bf16x8*)(wTs + ((size_t)pl * HID + h0w + n * 16 + row) * 8);
            acc[0][n] = __builtin_amdgcn_mfma_f32_16x16x32_bf16(a0, bb, acc[0][n], 0, 0, 0);
            acc[1][n] = __builtin_amdgcn_mfma_f32_16x16x32_bf16(a1, bb, acc[1][n], 0, 0, 0);
        }
    }
    __syncthreads();    // agg LDS reads complete before epilogue overlay

    // ---- phase 3: epilogue: bias/relu -> LDS tile -> coalesced stores -----
    #pragma unroll
    for (int n = 0; n < 2; ++n) {
        float bh = bias[h0w + n * 16 + row];
        #pragma unroll
        for (int i = 0; i < 2; ++i) {
            #pragma unroll
            for (int r = 0; r < 4; ++r) {
                int pt = ptw + i * 16 + quad * 4 + r;     // 0..63 in tile
                int hh = h0w + n * 16 + row;              // 0..127
                float vv = acc[i][n][r] + bh;
                if (RELU) vv = fmaxf(vv, 0.f);
                if (OUT_BF16) obf[pt][hh] = f2bf(vv);
                else          of32[pt][hh] = vv;
            }
        }
    }
    __syncthreads();

    if (OUT_BF16) {
        unsigned short* o = (unsigned short*)outv;        // row-major bf16
        #pragma unroll
        for (int q = 0; q < 2; ++q) {
            int task = q * 512 + threadIdx.x;     // 1024 = 64 pts x 16 chunks
            int pt = task >> 4, cc = task & 15;
            *(uint4*)(o + (size_t)(p0 + pt) * HID + cc * 8) =
                *(const uint4*)&obf[pt][cc * 8];
        }
    } else {
        float* o = (float*)outv;                          // row-major f32
        #pragma unroll
        for (int q = 0; q < 4; ++q) {
            int task = q * 512 + threadIdx.x;     // 2048 = 64 rows x 32 chunks
            int rr = task >> 5, ch = task & 31;
            *(float4*)(o + (size_t)(p0 + rr) * HID + ch * 4) =
                *(const float4*)&of32[rr][ch * 4];
        }
    }
}

// ---------------------------------------------------------------------------
extern "C" void kernel_launch(void* const* d_in, const int* in_sizes, int n_in,
                              void* d_out, int out_size, void* d_ws, size_t ws_size,
                              hipStream_t stream)
{
    const float* pc  = (const float*)d_in[0];
    const float* W1r = (const float*)d_in[1];
    const float* b1  = (const float*)d_in[2];
    const float* W1s = (const float*)d_in[3];
    const float* W2r = (const float*)d_in[4];
    const float* b2  = (const float*)d_in[5];
    const float* W2s = (const float*)d_in[6];
    const float* W3r = (const float*)d_in[7];
    const float* b3  = (const float*)d_in[8];
    const float* W3s = (const float*)d_in[9];
    float* out = (float*)d_out;

    char* ws = (char*)d_ws;
    const size_t MB = 1024 * 1024;
    const size_t XSZ = (size_t)NPOINTS * HID * 2;                // 8.39 MB
    int*            nbr  = (int*)ws;                             // 2 MB
    unsigned short* x1   = (unsigned short*)(ws + 2 * MB);       // row-major
    unsigned short* x2   = (unsigned short*)(ws + 2 * MB + XSZ); // row-major
    unsigned short* wT   = (unsigned short*)(ws + 2 * MB + 2 * XSZ);
    unsigned short* w2rT = wT;
    unsigned short* w2sT = wT + 16384;
    unsigned short* w3rT = wT + 32768;
    unsigned short* w3sT = wT + 49152;

    // launch 1: kNN + fused layer 1 (+32 trailing blocks do weight cvt)
    knn_kernel<<<KNN_BLOCKS + 32, 512, 0, stream>>>(
        pc, nbr, W1r, b1, W1s, x1, W2r, W2s, W3r, W3s, wT);

    // launch 2: fused gather+conv2 -> x2 (row-major bf16, relu)
    fusedconv_kernel<true, true><<<NPOINTS / 64, 512, 0, stream>>>(
        x1, nbr, w2rT, w2sT, b2, x2);

    // launch 3: fused gather+conv3 -> out (row-major f32)
    fusedconv_kernel<false, false><<<NPOINTS / 64, 512, 0, stream>>>(
        x2, nbr, w3rT, w3sT, b3, out);
}

// Round 12
// 156.452 us; speedup vs baseline: 1.1964x; 1.0881x over previous
//
#include <hip/hip_runtime.h>
#include <math.h>

#define NPTS 2048
#define BATCH 16
#define KNN 16
#define HID 128
#define NPOINTS (BATCH * NPTS)   // 32768
#define RPB 8          // rows (queries) per block = waves per block
#define CAP 64         // compacted-candidate capacity per query (m ~ 18.4 avg)
#define KNN_BLOCKS (NPOINTS / RPB)   // 4096

typedef __attribute__((ext_vector_type(8))) short bf16x8;
typedef __attribute__((ext_vector_type(4))) float f32x4;

__device__ inline unsigned short f2bf(float f) {    // RNE f32 -> bf16 bits
    unsigned u = __float_as_uint(f);
    return (unsigned short)((u + 0x7FFFu + ((u >> 16) & 1u)) >> 16);
}
__device__ inline float bflo(unsigned v) { return __uint_as_float(v << 16); }
__device__ inline float bfhi(unsigned v) { return __uint_as_float(v & 0xFFFF0000u); }

// x1/x2 ROW-MAJOR bf16 [32768][128]; weights chunked-T (wT[cc][h][8]).
//
// R21 == R17 restore (best measured: 156.7us total). Variant ledger:
//   R17 separate-b32 ckey/cidx, reg-resident key[32], 512-thr blocks: 42us
//   R18 2-queries/wave: 86us (VGPR 76 > 64-reg occupancy cliff)
//   R19 1024-thr blocks: 63us (workgroup granularity loss)
//   R20 packed-u64 cand: 57us (b64 broadcast 2x bytes + 64-bit compares)
// Budget: harness reset ~107us (268MB fill @73% HBM peak, not addressable)
// + knn ~42 (within ~1.5x of its 15us LDS-BW floor, 100% occupancy ceiling)
// + convs ~8 (L2-BW + MFMA bound). No remaining lever >3%.

// ---------------------------------------------------------------------------
// kNN + fused layer 1. One wave per query row.
// ---------------------------------------------------------------------------
__global__ __launch_bounds__(512) void knn_kernel(
    const float* __restrict__ pc, int* __restrict__ nbr,
    const float* __restrict__ W1r, const float* __restrict__ b1,
    const float* __restrict__ W1s, unsigned short* __restrict__ x1,
    const float* __restrict__ W2r, const float* __restrict__ W2s,
    const float* __restrict__ W3r, const float* __restrict__ W3s,
    unsigned short* __restrict__ wT)
{
    __shared__ __align__(16) float4 pts[NPTS];              // 32 KB
    __shared__ unsigned ckey[RPB][CAP];                     // 2 KB
    __shared__ unsigned cidx[RPB][CAP];                     // 2 KB
    __shared__ __align__(16) unsigned short xst[RPB][HID];  // 2 KB

    if (blockIdx.x >= KNN_BLOCKS) {
        // ---- folded weight conversion: 32 blocks x 512 thr x 4 elems ------
        int g = (blockIdx.x - KNN_BLOCKS) * 2048 + (int)threadIdx.x * 4;
        #pragma unroll
        for (int u = 0; u < 4; ++u) {
            int g2 = g + u;
            int mm = g2 >> 14;
            int e = g2 & 16383;
            int r = e >> 7, cch = e & 127;
            const float* s = (mm == 0) ? W2r : (mm == 1) ? W2s
                           : (mm == 2) ? W3r : W3s;
            wT[mm * 16384 + ((cch >> 3) * 128 + r) * 8 + (cch & 7)] = f2bf(s[e]);
        }
        return;
    }

    const int b = blockIdx.x >> 8;                    // 256 blocks per batch
    const int rblk = blockIdx.x & 255;
    const float* p = pc + (size_t)b * NPTS * 3;

    for (int t = threadIdx.x; t < NPTS; t += 512) {
        float x = p[t * 3 + 0], y = p[t * 3 + 1], z = p[t * 3 + 2];
        pts[t] = make_float4(x, y, z, x * x + y * y + z * z);
    }
    __syncthreads();

    const int w = threadIdx.x >> 6;
    const int lane = threadIdx.x & 63;
    const int i = rblk * RPB + w;                     // query row in batch
    const float4 pi = pts[i];
    const float piw16 = pi.w + 16.0f;

    unsigned key[32];                                 // STATIC indexing only!
    unsigned km = 0xFFFFFFFFu;
    #pragma unroll
    for (int t = 0; t < 32; ++t) {
        float4 c = pts[t * 64 + lane];
        float dot = fmaf(pi.x, c.x, fmaf(pi.y, c.y, pi.z * c.z));
        float d2 = fmaf(-2.0f, dot, piw16 + c.w);
        key[t] = __float_as_uint(d2);
        km = min(km, key[t]);
    }

    // ---- T0 = 16th-smallest of the 64 per-lane minima (bitonic, parallel) -
    unsigned v = km;
    #pragma unroll
    for (int k = 2; k <= 64; k <<= 1) {
        #pragma unroll
        for (int j = k >> 1; j > 0; j >>= 1) {
            unsigned o = (unsigned)__shfl_xor((int)v, j, 64);
            bool sel = ((lane & k) == 0) == ((lane & j) == 0);
            v = sel ? min(v, o) : max(v, o);
        }
    }
    const unsigned T0 = (unsigned)__shfl((int)v, 15, 64);
    // >=16 candidates <= T0 and T0 >= true 16th => superset of the top-16.

    // ---- compaction: FULLY UNROLLED so key[t] stays in registers ----------
    unsigned base = 0;
    #pragma unroll
    for (int t = 0; t < 32; ++t) {
        bool pred = key[t] <= T0;
        unsigned long long mask = __ballot(pred);
        if (mask) {
            unsigned prefix = __builtin_amdgcn_mbcnt_hi(
                (unsigned)(mask >> 32),
                __builtin_amdgcn_mbcnt_lo((unsigned)mask, 0));
            unsigned pos = base + prefix;
            if (pred && pos < CAP) {
                ckey[w][pos] = key[t];
                cidx[w][pos] = (unsigned)(t * 64 + lane);
            }
            base += (unsigned)__popcll(mask);
        }
    }
    const int m = (int)base;

    int* out = nbr + ((size_t)b * NPTS + i) * KNN;
    float ax = 0.f, ay = 0.f, az = 0.f;               // fused position sum

    if (m <= CAP) {
        unsigned k0 = (lane < m) ? ckey[w][lane] : 0xFFFFFFFFu;
        int r0 = 0;
        #pragma unroll 2
        for (int jj = 0; jj < m; ++jj) {
            unsigned kj = ckey[w][jj];
            r0 += (kj < k0) || (kj == k0 && jj < lane);
        }
        if (lane < m && r0 < KNN) {
            unsigned j = cidx[w][lane];
            out[r0] = (int)j;
            float4 q = pts[j]; ax += q.x; ay += q.y; az += q.z;
        }
    } else {
        // exact fallback (never taken w/ random data; correctness only).
        // Recomputes d2 from LDS pts (same fmaf sequence -> identical bits)
        // so it never runtime-indexes key[] (which would force scratch).
        auto keyat = [&](int t) -> unsigned {
            float4 c = pts[t * 64 + lane];
            float dot = fmaf(pi.x, c.x, fmaf(pi.y, c.y, pi.z * c.z));
            float d2 = fmaf(-2.0f, dot, piw16 + c.w);
            return __float_as_uint(d2);
        };
        unsigned T = 0;
        #pragma unroll 1
        for (int bit = 31; bit >= 0; --bit) {
            unsigned trial = T | (1u << bit);
            int cnt = 0;
            #pragma unroll 1
            for (int t = 0; t < 32; ++t) cnt += (keyat(t) < trial);
            #pragma unroll
            for (int off = 32; off; off >>= 1)
                cnt += __shfl_xor(cnt, off, 64);
            if (cnt < KNN) T = trial;
        }
        unsigned bs = 0;
        #pragma unroll 1
        for (int t = 0; t < 32; ++t) {
            bool p1 = keyat(t) < T;
            unsigned long long mask = __ballot(p1);
            if (mask) {
                unsigned prefix = __builtin_amdgcn_mbcnt_hi(
                    (unsigned)(mask >> 32),
                    __builtin_amdgcn_mbcnt_lo((unsigned)mask, 0));
                if (p1) {
                    out[bs + prefix] = t * 64 + lane;
                    float4 q = pts[t * 64 + lane];
                    ax += q.x; ay += q.y; az += q.z;
                }
                bs += (unsigned)__popcll(mask);
            }
        }
        #pragma unroll 1
        for (int t = 0; t < 32 && bs < KNN; ++t) {
            bool p2 = keyat(t) == T;
            unsigned long long mask = __ballot(p2);
            if (mask) {
                unsigned prefix = __builtin_amdgcn_mbcnt_hi(
                    (unsigned)(mask >> 32),
                    __builtin_amdgcn_mbcnt_lo((unsigned)mask, 0));
                unsigned pos = bs + prefix;
                if (p2 && pos < KNN) {
                    out[pos] = t * 64 + lane;
                    float4 q = pts[t * 64 + lane];
                    ax += q.x; ay += q.y; az += q.z;
                }
                bs += (unsigned)__popcll(mask);
            }
        }
    }

    #pragma unroll
    for (int off = 32; off; off >>= 1) {
        ax += __shfl_xor(ax, off, 64);
        ay += __shfl_xor(ay, off, 64);
        az += __shfl_xor(az, off, 64);
    }

    // ---- fused layer 1 -> LDS stage -> row-major write --------------------
    #pragma unroll
    for (int hh = 0; hh < 2; ++hh) {
        int h = lane + hh * 64;
        float acc = b1[h];
        acc += W1r[h * 3 + 0] * ax + W1r[h * 3 + 1] * ay + W1r[h * 3 + 2] * az;
        acc += W1s[h * 3 + 0] * pi.x + W1s[h * 3 + 1] * pi.y + W1s[h * 3 + 2] * pi.z;
        xst[w][h] = f2bf(fmaxf(acc, 0.f));
    }
    __syncthreads();
    if (threadIdx.x < RPB * 16) {                 // 128 tasks x 16 B
        int pt = threadIdx.x >> 4, cc = threadIdx.x & 15;
        uint4 vv = *(const uint4*)&xst[pt][cc * 8];
        *(uint4*)&x1[((size_t)b * NPTS + rblk * RPB + pt) * HID + cc * 8] = vv;
    }
}

// ---------------------------------------------------------------------------
// Fused gather + GEMM conv (R13/R17 structure).
// ---------------------------------------------------------------------------
template <bool RELU, bool OUT_BF16>
__global__ __launch_bounds__(512) void fusedconv_kernel(
    const unsigned short* __restrict__ xR, const int* __restrict__ nbr,
    const unsigned short* __restrict__ wTr, const unsigned short* __restrict__ wTs,
    const float* __restrict__ bias, void* __restrict__ outv)
{
    // union: agg [16][64][8] bf16 (16KB) / epilogue bf16 [64][136] / f32 [64][132]
    __shared__ __align__(16) char smem[64 * 132 * 4];
    unsigned short (*agg)[64][8] = (unsigned short (*)[64][8])smem;
    unsigned short (*obf)[136] = (unsigned short (*)[136])smem;
    float (*of32)[132] = (float (*)[132])smem;

    const int p0 = blockIdx.x * 64;                   // global point base
    const int b = blockIdx.x >> 5;                    // 32 blocks per batch
    const unsigned short* xb = xR + (size_t)b * NPTS * HID;

    // ---- phase 1: neighbor gather into LDS agg tile -----------------------
    {
        const int pt = threadIdx.x >> 3;              // 0..63
        const int sub = threadIdx.x & 7;              // chunk planes sub, sub+8
        const int4* nr4 = (const int4*)(nbr + (size_t)(p0 + pt) * KNN);
        int4 n0 = nr4[0], n1 = nr4[1], n2 = nr4[2], n3 = nr4[3];
        int idx[16] = {n0.x, n0.y, n0.z, n0.w, n1.x, n1.y, n1.z, n1.w,
                       n2.x, n2.y, n2.z, n2.w, n3.x, n3.y, n3.z, n3.w};
        float s0[8] = {0, 0, 0, 0, 0, 0, 0, 0};
        float s1[8] = {0, 0, 0, 0, 0, 0, 0, 0};
        #pragma unroll
        for (int t = 0; t < KNN; ++t) {
            const unsigned short* rowp = xb + (size_t)idx[t] * HID + sub * 8;
            uint4 va = *(const uint4*)rowp;           // plane sub
            uint4 vb = *(const uint4*)(rowp + 64);    // plane sub+8
            s0[0] += bflo(va.x); s0[1] += bfhi(va.x);
            s0[2] += bflo(va.y); s0[3] += bfhi(va.y);
            s0[4] += bflo(va.z); s0[5] += bfhi(va.z);
            s0[6] += bflo(va.w); s0[7] += bfhi(va.w);
            s1[0] += bflo(vb.x); s1[1] += bfhi(vb.x);
            s1[2] += bflo(vb.y); s1[3] += bfhi(vb.y);
            s1[4] += bflo(vb.z); s1[5] += bfhi(vb.z);
            s1[6] += bflo(vb.w); s1[7] += bfhi(vb.w);
        }
        uint4 o0, o1;
        o0.x = (unsigned)f2bf(s0[0]) | ((unsigned)f2bf(s0[1]) << 16);
        o0.y = (unsigned)f2bf(s0[2]) | ((unsigned)f2bf(s0[3]) << 16);
        o0.z = (unsigned)f2bf(s0[4]) | ((unsigned)f2bf(s0[5]) << 16);
        o0.w = (unsigned)f2bf(s0[6]) | ((unsigned)f2bf(s0[7]) << 16);
        o1.x = (unsigned)f2bf(s1[0]) | ((unsigned)f2bf(s1[1]) << 16);
        o1.y = (unsigned)f2bf(s1[2]) | ((unsigned)f2bf(s1[3]) << 16);
        o1.z = (unsigned)f2bf(s1[4]) | ((unsigned)f2bf(s1[5]) << 16);
        o1.w = (unsigned)f2bf(s1[6]) | ((unsigned)f2bf(s1[7]) << 16);
        *(uint4*)agg[sub][pt] = o0;
        *(uint4*)agg[sub + 8][pt] = o1;
    }
    __syncthreads();

    // ---- phase 2: MFMA ----------------------------------------------------
    const int wv = threadIdx.x >> 6;
    const int lane = threadIdx.x & 63;
    const int ptw = (wv & 1) * 32;                // 0 / 32
    const int h0w = (wv >> 1) * 32;               // 0 / 32 / 64 / 96
    const int row = lane & 15;
    const int quad = lane >> 4;

    f32x4 acc[2][2];
    #pragma unroll
    for (int i = 0; i < 2; ++i)
        #pragma unroll
        for (int n = 0; n < 2; ++n) acc[i][n] = (f32x4){0, 0, 0, 0};

    // agg @ Wr^T (A-frags from LDS)
    #pragma unroll
    for (int kc = 0; kc < 4; ++kc) {
        const int pl = quad + 4 * kc;             // chunk plane = k/8
        bf16x8 a0 = *(const bf16x8*)agg[pl][ptw + row];
        bf16x8 a1 = *(const bf16x8*)agg[pl][ptw + 16 + row];
        #pragma unroll
        for (int n = 0; n < 2; ++n) {
            bf16x8 bb = *(const bf16x8*)(wTr + ((size_t)pl * HID + h0w + n * 16 + row) * 8);
            acc[0][n] = __builtin_amdgcn_mfma_f32_16x16x32_bf16(a0, bb, acc[0][n], 0, 0, 0);
            acc[1][n] = __builtin_amdgcn_mfma_f32_16x16x32_bf16(a1, bb, acc[1][n], 0, 0, 0);
        }
    }
    // x @ Ws^T (A-frags from row-major global; kc loop covers full 256B row)
    #pragma unroll
    for (int kc = 0; kc < 4; ++kc) {
        const int pl = quad + 4 * kc;
        bf16x8 a0 = *(const bf16x8*)(xR + (size_t)(p0 + ptw + row) * HID + pl * 8);
        bf16x8 a1 = *(const bf16x8*)(xR + (size_t)(p0 + ptw + 16 + row) * HID + pl * 8);
        #pragma unroll
        for (int n = 0; n < 2; ++n) {
            bf16x8 bb = *(const bf16x8*)(wTs + ((size_t)pl * HID + h0w + n * 16 + row) * 8);
            acc[0][n] = __builtin_amdgcn_mfma_f32_16x16x32_bf16(a0, bb, acc[0][n], 0, 0, 0);
            acc[1][n] = __builtin_amdgcn_mfma_f32_16x16x32_bf16(a1, bb, acc[1][n], 0, 0, 0);
        }
    }
    __syncthreads();    // agg LDS reads complete before epilogue overlay

    // ---- phase 3: epilogue: bias/relu -> LDS tile -> coalesced stores -----
    #pragma unroll
    for (int n = 0; n < 2; ++n) {
        float bh = bias[h0w + n * 16 + row];
        #pragma unroll
        for (int i = 0; i < 2; ++i) {
            #pragma unroll
            for (int r = 0; r < 4; ++r) {
                int pt = ptw + i * 16 + quad * 4 + r;     // 0..63 in tile
                int hh = h0w + n * 16 + row;              // 0..127
                float vv = acc[i][n][r] + bh;
                if (RELU) vv = fmaxf(vv, 0.f);
                if (OUT_BF16) obf[pt][hh] = f2bf(vv);
                else          of32[pt][hh] = vv;
            }
        }
    }
    __syncthreads();

    if (OUT_BF16) {
        unsigned short* o = (unsigned short*)outv;        // row-major bf16
        #pragma unroll
        for (int q = 0; q < 2; ++q) {
            int task = q * 512 + threadIdx.x;     // 1024 = 64 pts x 16 chunks
            int pt = task >> 4, cc = task & 15;
            *(uint4*)(o + (size_t)(p0 + pt) * HID + cc * 8) =
                *(const uint4*)&obf[pt][cc * 8];
        }
    } else {
        float* o = (float*)outv;                          // row-major f32
        #pragma unroll
        for (int q = 0; q < 4; ++q) {
            int task = q * 512 + threadIdx.x;     // 2048 = 64 rows x 32 chunks
            int rr = task >> 5, ch = task & 31;
            *(float4*)(o + (size_t)(p0 + rr) * HID + ch * 4) =
                *(const float4*)&of32[rr][ch * 4];
        }
    }
}

// ---------------------------------------------------------------------------
extern "C" void kernel_launch(void* const* d_in, const int* in_sizes, int n_in,
                              void* d_out, int out_size, void* d_ws, size_t ws_size,
                              hipStream_t stream)
{
    const float* pc  = (const float*)d_in[0];
    const float* W1r = (const float*)d_in[1];
    const float* b1  = (const float*)d_in[2];
    const float* W1s = (const float*)d_in[3];
    const float* W2r = (const float*)d_in[4];
    const float* b2  = (const float*)d_in[5];
    const float* W2s = (const float*)d_in[6];
    const float* W3r = (const float*)d_in[7];
    const float* b3  = (const float*)d_in[8];
    const float* W3s = (const float*)d_in[9];
    float* out = (float*)d_out;

    char* ws = (char*)d_ws;
    const size_t MB = 1024 * 1024;
    const size_t XSZ = (size_t)NPOINTS * HID * 2;                // 8.39 MB
    int*            nbr  = (int*)ws;                             // 2 MB
    unsigned short* x1   = (unsigned short*)(ws + 2 * MB);       // row-major
    unsigned short* x2   = (unsigned short*)(ws + 2 * MB + XSZ); // row-major
    unsigned short* wT   = (unsigned short*)(ws + 2 * MB + 2 * XSZ);
    unsigned short* w2rT = wT;
    unsigned short* w2sT = wT + 16384;
    unsigned short* w3rT = wT + 32768;
    unsigned short* w3sT = wT + 49152;

    // launch 1: kNN + fused layer 1 (+32 trailing blocks do weight cvt)
    knn_kernel<<<KNN_BLOCKS + 32, 512, 0, stream>>>(
        pc, nbr, W1r, b1, W1s, x1, W2r, W2s, W3r, W3s, wT);

    // launch 2: fused gather+conv2 -> x2 (row-major bf16, relu)
    fusedconv_kernel<true, true><<<NPOINTS / 64, 512, 0, stream>>>(
        x1, nbr, w2rT, w2sT, b2, x2);

    // launch 3: fused gather+conv3 -> out (row-major f32)
    fusedconv_kernel<false, false><<<NPOINTS / 64, 512, 0, stream>>>(
        x2, nbr, w3rT, w3sT, b3, out);
}